// Round 1
// baseline (1091.816 us; speedup 1.0000x reference)
//
#include <hip/hip_runtime.h>

// ============================================================================
// Hybrid matrix prefix scan:  res[k] = x @ (m_0 ... m_{k-1}),  N=1024, D=256.
//
// Scheme (all intermediates stored as DEVIATIONS P - I in bf16; combine is
// exact on deviations: dev(XY) = devX + devY + devX@devY):
//   L1a: tmpA[c] = dev(m[4c] @ m[4c+1])                 (256 matmuls)
//   L1b: regB[c] = tmpA[c]  (*) E(m[4c+2])              (256)
//   L1c: regA[c] = regB[c]  (*) E(m[4c+3])  = Q[c]      (256)  span 4
//   L2 : Q2[d]   = Q[2d]    (*) Q[2d+1]                 (128)  span 8
//   L3 : Q4[e]   = Q2[2e]   (*) Q2[2e+1]                (64)   span 16
//   L4 : R[f]    = Q4[2f]   (*) Q4[2f+1]                (32)   span 32
//   scan_top: w[f] = res[32f]  (1 WG, 32 sequential dev mat-vecs over R)
//   descend x3: w -> u4 -> u2 -> u (prefix vectors at strides 16/8/4 chunks,
//               using EVEN-indexed nodes of each level)
//   bottom: 256 WGs, chunk c: write res[4c]=u[c], then 3 (4 for c=255) exact
//           fp32 mat-vecs over m emitting res[4c+1..].
// Total matmul work = 992 * 33.5 MFLOP = 33.2 GFLOP (vs 68.7 for full scan).
// ws layout (need 67,600,384 B):
//   [0,32MiB)  regA: tmpA -> final Q        (bf16 dev)
//   [32,64MiB) regB: L1b temp -> Q2(16MiB)+Q4(8MiB)+R(4MiB)
//   [64MiB+..) fp32 vectors: w(32x256) u4(64x256) u2(128x256) u(256x256)
// Round 1: fp32 VALU GEMM core (structure-correct). Round 2+: MFMA bf16.
// ============================================================================

#define D 256
#define DD 65536

__device__ __forceinline__ float bf2f(unsigned short u) {
  return __uint_as_float(((unsigned)u) << 16);
}
__device__ __forceinline__ unsigned short f2bf(float f) {
  unsigned u = __float_as_uint(f);
  u += 0x7FFFu + ((u >> 16) & 1u);          // round-to-nearest-even
  return (unsigned short)(u >> 16);
}

// out[mat] = devA + devB + devA @ devB   (256x256 row-major, bf16 out)
// A/B source: fp32 raw matrix (implicit -I) if *F non-null, else bf16 dev.
__global__ __launch_bounds__(256) void gemm_dev(
    const float* __restrict__ aF, const unsigned short* __restrict__ aBf,
    long aMul, long aOff,
    const float* __restrict__ bF, const unsigned short* __restrict__ bBf,
    long bMul, long bOff,
    unsigned short* __restrict__ out)
{
  __shared__ float As[16][68];   // [k][row], padded: conflict-free float4
  __shared__ float Bs[16][68];   // [k][col]

  const int  bx   = blockIdx.x;
  const long mat  = bx >> 4;
  const int  tile = bx & 15;
  const int  bi   = tile >> 2, bj = tile & 3;     // 64x64 output tile
  const long aBase = (mat * aMul + aOff) * (long)DD;
  const long bBase = (mat * bMul + bOff) * (long)DD;

  const int t  = threadIdx.x;
  const int tx = t & 15, ty = t >> 4;             // 16x16 threads, 4x4 each
  const int ar = t & 63, ak4 = (t >> 6) << 2;     // A staging map
  const int bk = t >> 4, bj4 = (t & 15) << 2;     // B staging map (coalesced)

  float acc[4][4] = {{0.f,0.f,0.f,0.f},{0.f,0.f,0.f,0.f},
                     {0.f,0.f,0.f,0.f},{0.f,0.f,0.f,0.f}};

  for (int kt = 0; kt < 16; ++kt) {
    const int k0 = kt << 4;
    {   // stage A (64 rows x 16 k), transposed -> As[k][row]
      const int gi = (bi << 6) + ar;
      const int gk = k0 + ak4;
      if (aF) {
        const float4 v = *(const float4*)(aF + aBase + (long)gi * D + gk);
        As[ak4 + 0][ar] = v.x - ((gi == gk + 0) ? 1.f : 0.f);
        As[ak4 + 1][ar] = v.y - ((gi == gk + 1) ? 1.f : 0.f);
        As[ak4 + 2][ar] = v.z - ((gi == gk + 2) ? 1.f : 0.f);
        As[ak4 + 3][ar] = v.w - ((gi == gk + 3) ? 1.f : 0.f);
      } else {
        const ushort4 v = *(const ushort4*)(aBf + aBase + (long)gi * D + gk);
        As[ak4 + 0][ar] = bf2f(v.x);
        As[ak4 + 1][ar] = bf2f(v.y);
        As[ak4 + 2][ar] = bf2f(v.z);
        As[ak4 + 3][ar] = bf2f(v.w);
      }
    }
    {   // stage B (16 k x 64 cols) -> Bs[k][col]
      const int gk = k0 + bk;
      const int gj = (bj << 6) + bj4;
      if (bF) {
        float4 v = *(const float4*)(bF + bBase + (long)gk * D + gj);
        if (gk >= gj && gk < gj + 4) ((float*)&v)[gk - gj] -= 1.f;
        *(float4*)&Bs[bk][bj4] = v;
      } else {
        const ushort4 v = *(const ushort4*)(bBf + bBase + (long)gk * D + gj);
        Bs[bk][bj4 + 0] = bf2f(v.x);
        Bs[bk][bj4 + 1] = bf2f(v.y);
        Bs[bk][bj4 + 2] = bf2f(v.z);
        Bs[bk][bj4 + 3] = bf2f(v.w);
      }
    }
    __syncthreads();
#pragma unroll
    for (int k = 0; k < 16; ++k) {
      const float4 a4 = *(const float4*)&As[k][ty << 2];
      const float4 b4 = *(const float4*)&Bs[k][tx << 2];
      acc[0][0] += a4.x*b4.x; acc[0][1] += a4.x*b4.y;
      acc[0][2] += a4.x*b4.z; acc[0][3] += a4.x*b4.w;
      acc[1][0] += a4.y*b4.x; acc[1][1] += a4.y*b4.y;
      acc[1][2] += a4.y*b4.z; acc[1][3] += a4.y*b4.w;
      acc[2][0] += a4.z*b4.x; acc[2][1] += a4.z*b4.y;
      acc[2][2] += a4.z*b4.z; acc[2][3] += a4.z*b4.w;
      acc[3][0] += a4.w*b4.x; acc[3][1] += a4.w*b4.y;
      acc[3][2] += a4.w*b4.z; acc[3][3] += a4.w*b4.w;
    }
    __syncthreads();
  }

  // epilogue: out = acc + devA + devB, store bf16 (4 at a time)
  const long ob  = mat * (long)DD;
  const int  gj0 = (bj << 6) + (tx << 2);
#pragma unroll
  for (int r = 0; r < 4; ++r) {
    const int gi = (bi << 6) + (ty << 2) + r;
    float s[4];
#pragma unroll
    for (int q = 0; q < 4; ++q) {
      const int gj = gj0 + q;
      const long off = (long)gi * D + gj;
      const float aEl = aF ? (aF[aBase + off] - (gi == gj ? 1.f : 0.f))
                           : bf2f(aBf[aBase + off]);
      const float bEl = bF ? (bF[bBase + off] - (gi == gj ? 1.f : 0.f))
                           : bf2f(bBf[bBase + off]);
      s[q] = acc[r][q] + aEl + bEl;
    }
    ushort4 o;
    o.x = f2bf(s[0]); o.y = f2bf(s[1]); o.z = f2bf(s[2]); o.w = f2bf(s[3]);
    *(ushort4*)(out + ob + (long)gi * D + gj0) = o;
  }
}

// 1 WG: w[f] = prefix vector at matrix 32f, f=0..31, via sequential dev matvec
__global__ __launch_bounds__(256) void scan_top(
    const float* __restrict__ x, const unsigned short* __restrict__ R,
    float* __restrict__ w)
{
  __shared__ float v[D];
  const int t = threadIdx.x;
  v[t] = x[t];
  __syncthreads();
  for (int f = 0; f < 32; ++f) {
    w[f * D + t] = v[t];
    const unsigned short* M = R + (long)f * DD;
    float acc = v[t];
    for (int i = 0; i < D; i += 4) {
      const float v0 = v[i], v1 = v[i+1], v2 = v[i+2], v3 = v[i+3];
      acc += v0 * bf2f(M[(long)(i  ) * D + t]);
      acc += v1 * bf2f(M[(long)(i+1) * D + t]);
      acc += v2 * bf2f(M[(long)(i+2) * D + t]);
      acc += v3 * bf2f(M[(long)(i+3) * D + t]);
    }
    __syncthreads();
    v[t] = acc;
    __syncthreads();
  }
}

// WG g: dst[2g] = src[g]; dst[2g+1] = src[g] applied to dev-matrix mats[2g]
__global__ __launch_bounds__(256) void descend(
    const float* __restrict__ src, const unsigned short* __restrict__ mats,
    float* __restrict__ dst)
{
  __shared__ float v[D];
  const int g = blockIdx.x, t = threadIdx.x;
  v[t] = src[(long)g * D + t];
  __syncthreads();
  dst[(long)(2 * g) * D + t] = v[t];
  const unsigned short* M = mats + (long)(2 * g) * DD;
  float acc = v[t];
  for (int i = 0; i < D; i += 4) {
    const float v0 = v[i], v1 = v[i+1], v2 = v[i+2], v3 = v[i+3];
    acc += v0 * bf2f(M[(long)(i  ) * D + t]);
    acc += v1 * bf2f(M[(long)(i+1) * D + t]);
    acc += v2 * bf2f(M[(long)(i+2) * D + t]);
    acc += v3 * bf2f(M[(long)(i+3) * D + t]);
  }
  dst[(long)(2 * g + 1) * D + t] = acc;
}

// WG c: res[4c] = u[c]; then exact fp32 matvecs over m for res[4c+1..]
__global__ __launch_bounds__(256) void bottom(
    const float* __restrict__ u, const float* __restrict__ m,
    float* __restrict__ out)
{
  __shared__ float v[D];
  const int c = blockIdx.x, t = threadIdx.x;
  v[t] = u[(long)c * D + t];
  __syncthreads();
  out[(long)(4 * c) * D + t] = v[t];
  const int steps = (c == 255) ? 4 : 3;
  for (int s = 0; s < steps; ++s) {
    const float* M = m + (long)(4 * c + s) * DD;
    float acc = 0.f;
    for (int i = 0; i < D; i += 4) {
      const float v0 = v[i], v1 = v[i+1], v2 = v[i+2], v3 = v[i+3];
      acc += v0 * M[(long)(i  ) * D + t];
      acc += v1 * M[(long)(i+1) * D + t];
      acc += v2 * M[(long)(i+2) * D + t];
      acc += v3 * M[(long)(i+3) * D + t];
    }
    __syncthreads();
    v[t] = acc;
    __syncthreads();
    out[(long)(4 * c + s + 1) * D + t] = acc;
  }
}

// correctness-only fallback if ws is too small: fully sequential chain
__global__ __launch_bounds__(256) void fallback_seq(
    const float* __restrict__ x, const float* __restrict__ m,
    float* __restrict__ out)
{
  __shared__ float v[D];
  const int t = threadIdx.x;
  v[t] = x[t];
  __syncthreads();
  for (int k = 0; k < 1024; ++k) {
    out[(long)k * D + t] = v[t];
    const float* M = m + (long)k * DD;
    float acc = 0.f;
    for (int i = 0; i < D; ++i) acc += v[i] * M[(long)i * D + t];
    __syncthreads();
    v[t] = acc;
    __syncthreads();
  }
  out[(long)1024 * D + t] = v[t];
}

extern "C" void kernel_launch(void* const* d_in, const int* in_sizes, int n_in,
                              void* d_out, int out_size, void* d_ws, size_t ws_size,
                              hipStream_t stream) {
  const float* x = (const float*)d_in[0];   // [1,256] fp32
  const float* m = (const float*)d_in[1];   // [1024,256,256] fp32
  float* out = (float*)d_out;               // [1025,256] fp32

  const size_t NEED = 67600384;             // 64 MiB + 480 KiB
  if (ws_size < NEED) {
    fallback_seq<<<1, 256, 0, stream>>>(x, m, out);
    return;
  }

  char* w8 = (char*)d_ws;
  unsigned short* regA = (unsigned short*)(w8);              // 32 MiB
  unsigned short* regB = (unsigned short*)(w8 + 33554432);   // 32 MiB
  unsigned short* Q2   = regB;                               // 16 MiB
  unsigned short* Q4   = (unsigned short*)(w8 + 50331648);   // 8 MiB
  unsigned short* Rm   = (unsigned short*)(w8 + 58720256);   // 4 MiB
  float* wv = (float*)(w8 + 67108864);
  float* u4 = wv + 32 * D;
  float* u2 = u4 + 64 * D;
  float* uu = u2 + 128 * D;

  const dim3 blk(256);
  // up-sweep: chunk products (span 4) via chain, then binary tree to span 32
  gemm_dev<<<dim3(256 * 16), blk, 0, stream>>>(m, nullptr, 4, 0, m, nullptr, 4, 1, regA);
  gemm_dev<<<dim3(256 * 16), blk, 0, stream>>>(nullptr, regA, 1, 0, m, nullptr, 4, 2, regB);
  gemm_dev<<<dim3(256 * 16), blk, 0, stream>>>(nullptr, regB, 1, 0, m, nullptr, 4, 3, regA);
  gemm_dev<<<dim3(128 * 16), blk, 0, stream>>>(nullptr, regA, 2, 0, nullptr, regA, 2, 1, Q2);
  gemm_dev<<<dim3(64 * 16),  blk, 0, stream>>>(nullptr, Q2,   2, 0, nullptr, Q2,   2, 1, Q4);
  gemm_dev<<<dim3(32 * 16),  blk, 0, stream>>>(nullptr, Q4,   2, 0, nullptr, Q4,   2, 1, Rm);
  // top sequential scan over the 32 span-32 products
  scan_top<<<dim3(1), blk, 0, stream>>>(x, Rm, wv);
  // vector down-sweep
  descend<<<dim3(32),  blk, 0, stream>>>(wv, Q4,   u4);
  descend<<<dim3(64),  blk, 0, stream>>>(u4, Q2,   u2);
  descend<<<dim3(128), blk, 0, stream>>>(u2, regA, uu);
  // bottom: exact fp32 matvecs over m, emit all output rows
  bottom<<<dim3(256), blk, 0, stream>>>(uu, m, out);
}

// Round 2
// 1034.643 us; speedup vs baseline: 1.0553x; 1.0553x over previous
//
#include <hip/hip_runtime.h>

// ============================================================================
// Hybrid matrix prefix scan:  res[k] = x @ (m_0 ... m_{k-1}),  N=1024, D=256.
// Deviation form everywhere: store P - I in bf16; combine is exact:
//   dev(XY) = devX + devY + devX@devY.
// Up-sweep (MFMA bf16): chunk(4) chain -> tree to span-128 (8 mats).
// Top: 8-step sequential vector scan; down-sweep: 5 descend levels + bottom
// (exact fp32 mat-vecs over m). Matmul work ~33.8 GFLOP vs 68.7 full scan.
// Round 2: MFMA 16x16x32 bf16 up-sweep (64x64 tile, BK=128, LDS transpose
// staging for B), 1024-thread K-split vector kernels, tree extended 2 levels.
// ============================================================================

#define D 256
#define DD 65536

typedef __attribute__((ext_vector_type(8))) short short8;
typedef __attribute__((ext_vector_type(4))) float f4;

__device__ __forceinline__ float bf2f(unsigned short u) {
  return __uint_as_float(((unsigned)u) << 16);
}
__device__ __forceinline__ unsigned short f2bf(float f) {
  unsigned u = __float_as_uint(f);
  u += 0x7FFFu + ((u >> 16) & 1u);          // round-to-nearest-even
  return (unsigned short)(u >> 16);
}
// dev element at [gi][gj]: fp32 raw (subtract I) or bf16 dev source
__device__ __forceinline__ float devAt(const float* F, const unsigned short* Bf,
                                       long base, int gi, int gj) {
  if (F) {
    float v = F[base + (long)gi * D + gj];
    return (gi == gj) ? v - 1.f : v;
  }
  return bf2f(Bf[base + (long)gi * D + gj]);
}

// out[mat] = devA + devB + devA@devB   (bf16 dev out), MFMA 16x16x32 bf16.
// 64x64 tile per block (16 blocks/mat), 4 waves, wave w rows [16w,16w+16).
// K tiled in halves of 128. As[m][k] row-major; Bs[n][k] (transposed staging).
__global__ __launch_bounds__(256) void gemm_mfma(
    const float* __restrict__ aF, const unsigned short* __restrict__ aBf,
    long aMul, long aOff,
    const float* __restrict__ bF, const unsigned short* __restrict__ bBf,
    long bMul, long bOff,
    unsigned short* __restrict__ out)
{
  constexpr int LS = 136;                  // 272B row: bank-step 4 -> 2-way(free)
  __shared__ unsigned short As[64 * LS];
  __shared__ unsigned short Bs[64 * LS];

  const int  bx   = blockIdx.x;
  const long mat  = bx >> 4;
  const int  tile = bx & 15;
  const int  m0 = (tile >> 2) << 6, n0 = (tile & 3) << 6;
  const long aBase = (mat * aMul + aOff) * (long)DD;
  const long bBase = (mat * bMul + bOff) * (long)DD;
  const int t = threadIdx.x;
  const int w = t >> 6, l = t & 63, lm = l & 15, lq = l >> 4;

  f4 acc[4] = {{0.f,0.f,0.f,0.f},{0.f,0.f,0.f,0.f},
               {0.f,0.f,0.f,0.f},{0.f,0.f,0.f,0.f}};

  for (int half = 0; half < 2; ++half) {
    const int kb = half << 7;
    // ---- stage A rows [m0,m0+64) x k [kb,kb+128) -> As[r][k] bf16 dev
    if (aF) {
#pragma unroll
      for (int p = 0; p < 8; ++p) {
        int c = (p << 8) + t;              // float4 chunks, 32/row
        int r = c >> 5, k4 = (c & 31) << 2;
        int gi = m0 + r, gk = kb + k4;
        float4 v = *(const float4*)(aF + aBase + (long)gi * D + gk);
        if (gi >= gk && gi < gk + 4) ((float*)&v)[gi - gk] -= 1.f;
        ushort4 o = { f2bf(v.x), f2bf(v.y), f2bf(v.z), f2bf(v.w) };
        *(ushort4*)&As[r * LS + k4] = o;
      }
    } else {
#pragma unroll
      for (int p = 0; p < 4; ++p) {
        int c = (p << 8) + t;              // 16B chunks, 16/row
        int r = c >> 4, k8 = (c & 15) << 3;
        uint4 v = *(const uint4*)(aBf + aBase + (long)(m0 + r) * D + kb + k8);
        *(uint4*)&As[r * LS + k8] = v;
      }
    }
    // ---- stage B cols [n0,n0+64) x k -> Bs[n][k] (transpose in regs)
    {
      const int n4 = (t & 15) << 2;        // 4 local cols
      const int k8 = (t >> 4) << 3;        // 8 k's
      unsigned short tmp[4][8];
      if (bF) {
#pragma unroll
        for (int kk = 0; kk < 8; ++kk) {
          int gk = kb + k8 + kk, gn = n0 + n4;
          float4 v = *(const float4*)(bF + bBase + (long)gk * D + gn);
          if (gk >= gn && gk < gn + 4) ((float*)&v)[gk - gn] -= 1.f;
          tmp[0][kk] = f2bf(v.x); tmp[1][kk] = f2bf(v.y);
          tmp[2][kk] = f2bf(v.z); tmp[3][kk] = f2bf(v.w);
        }
      } else {
#pragma unroll
        for (int kk = 0; kk < 8; ++kk) {
          ushort4 v = *(const ushort4*)(bBf + bBase + (long)(kb + k8 + kk) * D + n0 + n4);
          tmp[0][kk] = v.x; tmp[1][kk] = v.y; tmp[2][kk] = v.z; tmp[3][kk] = v.w;
        }
      }
#pragma unroll
      for (int j = 0; j < 4; ++j) {
        *(ushort4*)&Bs[(n4 + j) * LS + k8]     = *(ushort4*)&tmp[j][0];
        *(ushort4*)&Bs[(n4 + j) * LS + k8 + 4] = *(ushort4*)&tmp[j][4];
      }
    }
    __syncthreads();
    // ---- MFMA: A[m=lane&15][k=quad*8+j], B[k=quad*8+j][n=lane&15]
#pragma unroll
    for (int kt = 0; kt < 4; ++kt) {
      short8 a = *(const short8*)&As[(16 * w + lm) * LS + kt * 32 + lq * 8];
#pragma unroll
      for (int f = 0; f < 4; ++f) {
        short8 b = *(const short8*)&Bs[(16 * f + lm) * LS + kt * 32 + lq * 8];
        acc[f] = __builtin_amdgcn_mfma_f32_16x16x32_bf16(a, b, acc[f], 0, 0, 0);
      }
    }
    __syncthreads();
  }

  // ---- epilogue: out = acc + devA + devB; C/D: col=lane&15, row=quad*4+reg
  const long ob = mat * (long)DD;
#pragma unroll
  for (int f = 0; f < 4; ++f) {
    const int gj = n0 + 16 * f + lm;
#pragma unroll
    for (int r = 0; r < 4; ++r) {
      const int gi = m0 + 16 * w + lq * 4 + r;
      float s = acc[f][r] + devAt(aF, aBf, aBase, gi, gj)
                          + devAt(bF, bBf, bBase, gi, gj);
      out[ob + (long)gi * D + gj] = f2bf(s);
    }
  }
}

// 1 WG x 1024 threads: w8[g] = prefix vector at mat 128g, over span-128 devs
__global__ __launch_bounds__(1024) void scan_top8(
    const float* __restrict__ x, const unsigned short* __restrict__ S,
    float* __restrict__ w8)
{
  __shared__ float v[D];
  __shared__ float ps[4][D];
  const int t = threadIdx.x, col = t & 255, kq = t >> 8;
  if (t < D) v[t] = x[t];
  __syncthreads();
  for (int g = 0; g < 8; ++g) {
    if (t < D) w8[g * D + t] = v[t];
    const unsigned short* M = S + (long)g * DD + (long)(kq * 64) * D + col;
    float acc = 0.f;
#pragma unroll 8
    for (int i = 0; i < 64; ++i)
      acc += v[kq * 64 + i] * bf2f(M[(long)i * D]);
    ps[kq][col] = acc;
    __syncthreads();
    if (t < D) v[t] += ps[0][t] + ps[1][t] + ps[2][t] + ps[3][t];
    __syncthreads();
  }
}

// WG g (1024 thr): dst[2g] = src[g]; dst[2g+1] = src[g] @ (I + dev mats[2g])
__global__ __launch_bounds__(1024) void descend(
    const float* __restrict__ src, const unsigned short* __restrict__ mats,
    float* __restrict__ dst)
{
  __shared__ float v[D];
  __shared__ float ps[4][D];
  const int g = blockIdx.x, t = threadIdx.x, col = t & 255, kq = t >> 8;
  if (t < D) v[t] = src[(long)g * D + t];
  __syncthreads();
  if (t < D) dst[(long)(2 * g) * D + t] = v[t];
  const unsigned short* M = mats + (long)(2 * g) * DD + (long)(kq * 64) * D + col;
  float acc = 0.f;
#pragma unroll 8
  for (int i = 0; i < 64; ++i)
    acc += v[kq * 64 + i] * bf2f(M[(long)i * D]);
  ps[kq][col] = acc;
  __syncthreads();
  if (t < D)
    dst[(long)(2 * g + 1) * D + t] = v[t] + ps[0][t] + ps[1][t] + ps[2][t] + ps[3][t];
}

// WG c (1024 thr): res[4c] = u[c]; then 3 (4 for c=255) exact fp32 mat-vecs
__global__ __launch_bounds__(1024) void bottom(
    const float* __restrict__ u, const float* __restrict__ m,
    float* __restrict__ out)
{
  __shared__ float v[D];
  __shared__ float ps[4][D];
  const int c = blockIdx.x, t = threadIdx.x, col = t & 255, kq = t >> 8;
  if (t < D) v[t] = u[(long)c * D + t];
  __syncthreads();
  if (t < D) out[(long)(4 * c) * D + t] = v[t];
  const int steps = (c == 255) ? 4 : 3;
  for (int s = 0; s < steps; ++s) {
    const float* M = m + (long)(4 * c + s) * DD + (long)(kq * 64) * D + col;
    float acc = 0.f;
#pragma unroll 8
    for (int i = 0; i < 64; ++i)
      acc += v[kq * 64 + i] * M[(long)i * D];
    ps[kq][col] = acc;
    __syncthreads();
    if (t < D) {
      float s2 = ps[0][t] + ps[1][t] + ps[2][t] + ps[3][t];
      v[t] = s2;
      out[(long)(4 * c + s + 1) * D + t] = s2;
    }
    __syncthreads();
  }
}

// correctness-only fallback if ws is too small: fully sequential chain
__global__ __launch_bounds__(256) void fallback_seq(
    const float* __restrict__ x, const float* __restrict__ m,
    float* __restrict__ out)
{
  __shared__ float v[D];
  const int t = threadIdx.x;
  v[t] = x[t];
  __syncthreads();
  for (int k = 0; k < 1024; ++k) {
    out[(long)k * D + t] = v[t];
    const float* M = m + (long)k * DD;
    float acc = 0.f;
    for (int i = 0; i < D; ++i) acc += v[i] * M[(long)i * D + t];
    __syncthreads();
    v[t] = acc;
    __syncthreads();
  }
  out[(long)1024 * D + t] = v[t];
}

extern "C" void kernel_launch(void* const* d_in, const int* in_sizes, int n_in,
                              void* d_out, int out_size, void* d_ws, size_t ws_size,
                              hipStream_t stream) {
  const float* x = (const float*)d_in[0];   // [1,256] fp32
  const float* m = (const float*)d_in[1];   // [1024,256,256] fp32
  float* out = (float*)d_out;               // [1025,256] fp32

  const size_t NEED = 67624960;             // 63 MiB mats + 504 KiB vectors
  if (ws_size < NEED) {
    fallback_seq<<<1, 256, 0, stream>>>(x, m, out);
    return;
  }

  char* w8 = (char*)d_ws;
  unsigned short* regA = (unsigned short*)(w8);              // 32 MiB: tmp->Q(span4)
  unsigned short* regB = (unsigned short*)(w8 + 33554432);   // 32 MiB tmp
  unsigned short* Q2   = regB;                               // 16 MiB span-8
  unsigned short* Q4   = (unsigned short*)(w8 + 50331648);   // 8 MiB span-16
  unsigned short* Rm   = (unsigned short*)(w8 + 58720256);   // 4 MiB span-32
  unsigned short* S64  = (unsigned short*)(w8 + 62914560);   // 2 MiB span-64
  unsigned short* S128 = (unsigned short*)(w8 + 65011712);   // 1 MiB span-128
  float* wv  = (float*)(w8 + 67108864);
  float* w8v = wv;                 // 8 x 256
  float* w16 = wv + 2048;          // 16 x 256
  float* w32 = wv + 6144;          // 32 x 256
  float* u4  = wv + 14336;         // 64 x 256
  float* u2  = wv + 30720;         // 128 x 256
  float* uu  = wv + 63488;         // 256 x 256

  const dim3 blk(256), vblk(1024);
  // up-sweep: chunk products (span 4) via chain, then tree to span 128
  gemm_mfma<<<dim3(256*16), blk, 0, stream>>>(m, nullptr, 4, 0, m, nullptr, 4, 1, regA);
  gemm_mfma<<<dim3(256*16), blk, 0, stream>>>(nullptr, regA, 1, 0, m, nullptr, 4, 2, regB);
  gemm_mfma<<<dim3(256*16), blk, 0, stream>>>(nullptr, regB, 1, 0, m, nullptr, 4, 3, regA);
  gemm_mfma<<<dim3(128*16), blk, 0, stream>>>(nullptr, regA, 2, 0, nullptr, regA, 2, 1, Q2);
  gemm_mfma<<<dim3(64*16),  blk, 0, stream>>>(nullptr, Q2,   2, 0, nullptr, Q2,   2, 1, Q4);
  gemm_mfma<<<dim3(32*16),  blk, 0, stream>>>(nullptr, Q4,   2, 0, nullptr, Q4,   2, 1, Rm);
  gemm_mfma<<<dim3(16*16),  blk, 0, stream>>>(nullptr, Rm,   2, 0, nullptr, Rm,   2, 1, S64);
  gemm_mfma<<<dim3(8*16),   blk, 0, stream>>>(nullptr, S64,  2, 0, nullptr, S64,  2, 1, S128);
  // top sequential scan over the 8 span-128 products
  scan_top8<<<dim3(1), vblk, 0, stream>>>(x, S128, w8v);
  // vector down-sweep
  descend<<<dim3(8),   vblk, 0, stream>>>(w8v, S64,  w16);
  descend<<<dim3(16),  vblk, 0, stream>>>(w16, Rm,   w32);
  descend<<<dim3(32),  vblk, 0, stream>>>(w32, Q4,   u4);
  descend<<<dim3(64),  vblk, 0, stream>>>(u4,  Q2,   u2);
  descend<<<dim3(128), vblk, 0, stream>>>(u2,  regA, uu);
  // bottom: exact fp32 matvecs over m, emit all output rows
  bottom<<<dim3(256), vblk, 0, stream>>>(uu, m, out);
}

// Round 3
// 935.316 us; speedup vs baseline: 1.1673x; 1.1062x over previous
//
#include <hip/hip_runtime.h>

// ============================================================================
// Hybrid matrix prefix scan:  res[k] = x @ (m_0 ... m_{k-1}),  N=1024, D=256.
// Deviation form everywhere: store P - I in bf16; combine is exact:
//   dev(XY) = devX + devY + devX@devY.
// Round 3 gemm rewrite: fragment-order swizzled LDS (conflict-free ds_read_b128
// frag reads), full-K staging (one phase, 3 barriers), epilogue linear terms
// read from LDS (no global re-read), C via padded LDS restage -> coalesced
// uint4 stores (no write amplification).
// ============================================================================

#define D 256
#define DD 65536

typedef __attribute__((ext_vector_type(8))) short short8;
typedef __attribute__((ext_vector_type(4))) float f4;

__device__ __forceinline__ float bf2f(unsigned short u) {
  return __uint_as_float(((unsigned)u) << 16);
}
__device__ __forceinline__ unsigned short f2bf(float f) {
  unsigned u = __float_as_uint(f);
  u += 0x7FFFu + ((u >> 16) & 1u);          // round-to-nearest-even
  return (unsigned short)(u >> 16);
}
// fragment-order slot lane index: element (idx within 16-group, k) ->
// lane = ((idx&15) + 16*lq) ^ lq, lq = (k>>3)&3. The ^lq spreads staging
// writes across banks; frag reads are lane-contiguous (conflict-free).
#define LSWZ(i15, lq) (((((i15) & 15)) + ((lq) << 4)) ^ (lq))

// out[mat] = devA + devB + devA@devB (bf16 dev out), MFMA 16x16x32 bf16.
// 64x64 tile/block (16 blocks/mat), 4 waves, full K=256 staged once.
// As: rows [m0,m0+64) x k[0,256); Bs: cols [n0,n0+64) x k[0,256); both in
// fragment order: shorts addr = ((tile16*8 + (k>>5))*64 + LSWZ(idx,lq))*8 + (k&7).
__global__ __launch_bounds__(256) void gemm_mfma(
    const float* __restrict__ aF, const unsigned short* __restrict__ aBf,
    long aMul, long aOff,
    const float* __restrict__ bF, const unsigned short* __restrict__ bBf,
    long bMul, long bOff,
    unsigned short* __restrict__ out)
{
  __shared__ __attribute__((aligned(16))) unsigned short As[32768]; // A:0..16K, B:16K..32K
  unsigned short* Bs = As + 16384;

  const int  bx   = blockIdx.x;
  const long mat  = bx >> 4;
  const int  tile = bx & 15;
  const int  m0 = (tile >> 2) << 6, n0 = (tile & 3) << 6;
  const long aBase = (mat * aMul + aOff) * (long)DD;
  const long bBase = (mat * bMul + bOff) * (long)DD;
  const int t = threadIdx.x;
  const int w = t >> 6, l = t & 63, lm = l & 15, lq4 = l >> 4;
  const int lswz = l ^ lq4;

  // ---- stage A rows [m0,m0+64) x k[0,256)
  if (aF) {
#pragma unroll
    for (int p = 0; p < 16; ++p) {
      const int idx = (p << 10) + (t << 2);       // float index
      const int r = idx >> 8, k = idx & 255;      // k multiple of 4
      const int gi = m0 + r;
      float4 v = *(const float4*)(aF + aBase + (long)gi * D + k);
      if (gi >= k && gi < k + 4) ((float*)&v)[gi - k] -= 1.f;
      const int lq = (k >> 3) & 3;
      const int slot = (((r >> 4) << 3) + (k >> 5)) * 64 + LSWZ(r, lq);
      ushort4 o = { f2bf(v.x), f2bf(v.y), f2bf(v.z), f2bf(v.w) };
      *(ushort4*)&As[(slot << 3) + (k & 7)] = o;
    }
  } else {
#pragma unroll
    for (int p = 0; p < 8; ++p) {
      const int sidx = (p << 11) + (t << 3);      // short index, k mult of 8
      const int r = sidx >> 8, k = sidx & 255;
      const uint4 v = *(const uint4*)(aBf + aBase + (long)(m0 + r) * D + k);
      const int lq = (k >> 3) & 3;
      const int slot = (((r >> 4) << 3) + (k >> 5)) * 64 + LSWZ(r, lq);
      *(uint4*)&As[slot << 3] = v;
    }
  }
  // ---- stage B cols [n0,n0+64) x k[0,256) (register transpose)
  {
    const int n4 = (t & 15) << 2;
    const int kb0 = (t >> 4) << 3;
#pragma unroll
    for (int kp = 0; kp < 2; ++kp) {
      const int k8 = kb0 + (kp << 7);
      __attribute__((aligned(16))) unsigned short tmp[4][8];
      if (bF) {
#pragma unroll
        for (int kk = 0; kk < 8; ++kk) {
          const int gk = k8 + kk, gn = n0 + n4;
          float4 v = *(const float4*)(bF + bBase + (long)gk * D + gn);
          if (gk >= gn && gk < gn + 4) ((float*)&v)[gk - gn] -= 1.f;
          tmp[0][kk] = f2bf(v.x); tmp[1][kk] = f2bf(v.y);
          tmp[2][kk] = f2bf(v.z); tmp[3][kk] = f2bf(v.w);
        }
      } else {
#pragma unroll
        for (int kk = 0; kk < 8; ++kk) {
          const ushort4 v = *(const ushort4*)(bBf + bBase + (long)(k8 + kk) * D + n0 + n4);
          tmp[0][kk] = v.x; tmp[1][kk] = v.y; tmp[2][kk] = v.z; tmp[3][kk] = v.w;
        }
      }
      const int lq = (k8 >> 3) & 3, kt = k8 >> 5;
#pragma unroll
      for (int jj = 0; jj < 4; ++jj) {
        const int n = n4 + jj;
        const int slot = (((n >> 4) << 3) + kt) * 64 + LSWZ(n, lq);
        *(uint4*)&Bs[slot << 3] = *(const uint4*)&tmp[jj][0];
      }
    }
  }
  __syncthreads();

  // ---- MFMA: lane-contiguous frag reads, 32 MFMA/wave over K=256
  f4 acc[4] = {{0.f,0.f,0.f,0.f},{0.f,0.f,0.f,0.f},
               {0.f,0.f,0.f,0.f},{0.f,0.f,0.f,0.f}};
#pragma unroll
  for (int kt = 0; kt < 8; ++kt) {
    const short8 a = *(const short8*)&As[((((w << 3) + kt) << 6) + lswz) << 3];
#pragma unroll
    for (int f = 0; f < 4; ++f) {
      const short8 b = *(const short8*)&Bs[((((f << 3) + kt) << 6) + lswz) << 3];
      acc[f] = __builtin_amdgcn_mfma_f32_16x16x32_bf16(a, b, acc[f], 0, 0, 0);
    }
  }

  // ---- epilogue: s = acc + devA + devB, both read from resident LDS tiles
  float sv[4][4];
#pragma unroll
  for (int f = 0; f < 4; ++f) {
    const int gj_l = (f << 4) + lm;               // local col
    const int gj   = n0 + gj_l;                   // A's k index
    const int lqA  = (gj >> 3) & 3;
#pragma unroll
    for (int r = 0; r < 4; ++r) {
      const int gi_l = (w << 4) + (lq4 << 2) + r; // local row
      const int giG  = m0 + gi_l;                 // B's k index
      const int slotA = (((gi_l >> 4) << 3) + (gj >> 5)) * 64 + LSWZ(gi_l, lqA);
      const float da = bf2f(As[(slotA << 3) + (gj & 7)]);
      const int lqB  = (giG >> 3) & 3;
      const int slotB = (((gj_l >> 4) << 3) + (giG >> 5)) * 64 + LSWZ(gj_l, lqB);
      const float db = bf2f(Bs[(slotB << 3) + (giG & 7)]);
      sv[f][r] = acc[f][r] + da + db;
    }
  }
  __syncthreads();                                // all LDS reads done

  // ---- C restage (pitch 66: conflict-free b16 writes) then coalesced store
  unsigned short* Cs = As;                        // reuse (4224 shorts)
#pragma unroll
  for (int f = 0; f < 4; ++f)
#pragma unroll
    for (int r = 0; r < 4; ++r)
      Cs[((w << 4) + (lq4 << 2) + r) * 66 + (f << 4) + lm] = f2bf(sv[f][r]);
  __syncthreads();
  {
    const int row = t >> 2, c0 = (t & 3) << 4;    // 16 shorts per thread
    const unsigned int* Cw = (const unsigned int*)Cs;
    const int wb = row * 33 + ((t & 3) << 3);
    unsigned int wbuf[8];
#pragma unroll
    for (int i = 0; i < 8; ++i) wbuf[i] = Cw[wb + i];
    unsigned short* og = out + mat * (long)DD + (long)(m0 + row) * D + n0 + c0;
    uint4 o0 = { wbuf[0], wbuf[1], wbuf[2], wbuf[3] };
    uint4 o1 = { wbuf[4], wbuf[5], wbuf[6], wbuf[7] };
    *(uint4*)og = o0;
    *((uint4*)og + 1) = o1;
  }
}

// 1 WG x 1024 threads: w8[g] = prefix vector at mat 128g, over span-128 devs
__global__ __launch_bounds__(1024) void scan_top8(
    const float* __restrict__ x, const unsigned short* __restrict__ S,
    float* __restrict__ w8)
{
  __shared__ float v[D];
  __shared__ float ps[4][D];
  const int t = threadIdx.x, col = t & 255, kq = t >> 8;
  if (t < D) v[t] = x[t];
  __syncthreads();
  for (int g = 0; g < 8; ++g) {
    if (t < D) w8[g * D + t] = v[t];
    const unsigned short* M = S + (long)g * DD + (long)(kq * 64) * D + col;
    float acc = 0.f;
#pragma unroll 8
    for (int i = 0; i < 64; ++i)
      acc += v[kq * 64 + i] * bf2f(M[(long)i * D]);
    ps[kq][col] = acc;
    __syncthreads();
    if (t < D) v[t] += ps[0][t] + ps[1][t] + ps[2][t] + ps[3][t];
    __syncthreads();
  }
}

// WG g (1024 thr): dst[2g] = src[g]; dst[2g+1] = src[g] @ (I + dev mats[2g])
__global__ __launch_bounds__(1024) void descend(
    const float* __restrict__ src, const unsigned short* __restrict__ mats,
    float* __restrict__ dst)
{
  __shared__ float v[D];
  __shared__ float ps[4][D];
  const int g = blockIdx.x, t = threadIdx.x, col = t & 255, kq = t >> 8;
  if (t < D) v[t] = src[(long)g * D + t];
  __syncthreads();
  if (t < D) dst[(long)(2 * g) * D + t] = v[t];
  const unsigned short* M = mats + (long)(2 * g) * DD + (long)(kq * 64) * D + col;
  float acc = 0.f;
#pragma unroll 8
  for (int i = 0; i < 64; ++i)
    acc += v[kq * 64 + i] * bf2f(M[(long)i * D]);
  ps[kq][col] = acc;
  __syncthreads();
  if (t < D)
    dst[(long)(2 * g + 1) * D + t] = v[t] + ps[0][t] + ps[1][t] + ps[2][t] + ps[3][t];
}

// WG c (1024 thr): res[4c] = u[c]; then 3 (4 for c=255) exact fp32 mat-vecs
__global__ __launch_bounds__(1024) void bottom(
    const float* __restrict__ u, const float* __restrict__ m,
    float* __restrict__ out)
{
  __shared__ float v[D];
  __shared__ float ps[4][D];
  const int c = blockIdx.x, t = threadIdx.x, col = t & 255, kq = t >> 8;
  if (t < D) v[t] = u[(long)c * D + t];
  __syncthreads();
  if (t < D) out[(long)(4 * c) * D + t] = v[t];
  const int steps = (c == 255) ? 4 : 3;
  for (int s = 0; s < steps; ++s) {
    const float* M = m + (long)(4 * c + s) * DD + (long)(kq * 64) * D + col;
    float acc = 0.f;
#pragma unroll 8
    for (int i = 0; i < 64; ++i)
      acc += v[kq * 64 + i] * M[(long)i * D];
    ps[kq][col] = acc;
    __syncthreads();
    if (t < D) {
      float s2 = ps[0][t] + ps[1][t] + ps[2][t] + ps[3][t];
      v[t] = s2;
      out[(long)(4 * c + s + 1) * D + t] = s2;
    }
    __syncthreads();
  }
}

// correctness-only fallback if ws is too small: fully sequential chain
__global__ __launch_bounds__(256) void fallback_seq(
    const float* __restrict__ x, const float* __restrict__ m,
    float* __restrict__ out)
{
  __shared__ float v[D];
  const int t = threadIdx.x;
  v[t] = x[t];
  __syncthreads();
  for (int k = 0; k < 1024; ++k) {
    out[(long)k * D + t] = v[t];
    const float* M = m + (long)k * DD;
    float acc = 0.f;
    for (int i = 0; i < D; ++i) acc += v[i] * M[(long)i * D + t];
    __syncthreads();
    v[t] = acc;
    __syncthreads();
  }
  out[(long)1024 * D + t] = v[t];
}

extern "C" void kernel_launch(void* const* d_in, const int* in_sizes, int n_in,
                              void* d_out, int out_size, void* d_ws, size_t ws_size,
                              hipStream_t stream) {
  const float* x = (const float*)d_in[0];   // [1,256] fp32
  const float* m = (const float*)d_in[1];   // [1024,256,256] fp32
  float* out = (float*)d_out;               // [1025,256] fp32

  const size_t NEED = 67624960;             // 63 MiB mats + 504 KiB vectors
  if (ws_size < NEED) {
    fallback_seq<<<1, 256, 0, stream>>>(x, m, out);
    return;
  }

  char* w8 = (char*)d_ws;
  unsigned short* regA = (unsigned short*)(w8);              // 32 MiB: tmp->Q(span4)
  unsigned short* regB = (unsigned short*)(w8 + 33554432);   // 32 MiB tmp
  unsigned short* Q2   = regB;                               // 16 MiB span-8
  unsigned short* Q4   = (unsigned short*)(w8 + 50331648);   // 8 MiB span-16
  unsigned short* Rm   = (unsigned short*)(w8 + 58720256);   // 4 MiB span-32
  unsigned short* S64  = (unsigned short*)(w8 + 62914560);   // 2 MiB span-64
  unsigned short* S128 = (unsigned short*)(w8 + 65011712);   // 1 MiB span-128
  float* wv  = (float*)(w8 + 67108864);
  float* w8v = wv;                 // 8 x 256
  float* w16 = wv + 2048;          // 16 x 256
  float* w32 = wv + 6144;          // 32 x 256
  float* u4  = wv + 14336;         // 64 x 256
  float* u2  = wv + 30720;         // 128 x 256
  float* uu  = wv + 63488;         // 256 x 256

  const dim3 blk(256), vblk(1024);
  // up-sweep: chunk products (span 4) via chain, then tree to span 128
  gemm_mfma<<<dim3(256*16), blk, 0, stream>>>(m, nullptr, 4, 0, m, nullptr, 4, 1, regA);
  gemm_mfma<<<dim3(256*16), blk, 0, stream>>>(nullptr, regA, 1, 0, m, nullptr, 4, 2, regB);
  gemm_mfma<<<dim3(256*16), blk, 0, stream>>>(nullptr, regB, 1, 0, m, nullptr, 4, 3, regA);
  gemm_mfma<<<dim3(128*16), blk, 0, stream>>>(nullptr, regA, 2, 0, nullptr, regA, 2, 1, Q2);
  gemm_mfma<<<dim3(64*16),  blk, 0, stream>>>(nullptr, Q2,   2, 0, nullptr, Q2,   2, 1, Q4);
  gemm_mfma<<<dim3(32*16),  blk, 0, stream>>>(nullptr, Q4,   2, 0, nullptr, Q4,   2, 1, Rm);
  gemm_mfma<<<dim3(16*16),  blk, 0, stream>>>(nullptr, Rm,   2, 0, nullptr, Rm,   2, 1, S64);
  gemm_mfma<<<dim3(8*16),   blk, 0, stream>>>(nullptr, S64,  2, 0, nullptr, S64,  2, 1, S128);
  // top sequential scan over the 8 span-128 products
  scan_top8<<<dim3(1), vblk, 0, stream>>>(x, S128, w8v);
  // vector down-sweep
  descend<<<dim3(8),   vblk, 0, stream>>>(w8v, S64,  w16);
  descend<<<dim3(16),  vblk, 0, stream>>>(w16, Rm,   w32);
  descend<<<dim3(32),  vblk, 0, stream>>>(w32, Q4,   u4);
  descend<<<dim3(64),  vblk, 0, stream>>>(u4,  Q2,   u2);
  descend<<<dim3(128), vblk, 0, stream>>>(u2,  regA, uu);
  // bottom: exact fp32 matvecs over m, emit all output rows
  bottom<<<dim3(256), vblk, 0, stream>>>(uu, m, out);
}

// Round 4
// 577.682 us; speedup vs baseline: 1.8900x; 1.6191x over previous
//
#include <hip/hip_runtime.h>

// ============================================================================
// Hybrid matrix prefix scan:  res[k] = x @ (m_0 ... m_{k-1}),  N=1024, D=256.
// Deviation form everywhere: store P - I in bf16; combine is exact:
//   dev(XY) = devX + devY + devX@devY.
// Round 4: (a) XCD-aware block swizzle in gemm (all 16 tiles of a mat on one
// XCD -> L2-shared panels, 8 linear DRAM streams); (b) span2+span4 TREE
// replaces the 3-pass span-4 chain (one pass over m, split in halves to fit
// 67.6 MB ws); (c) no runtime-indexed diag fix.
// Up-sweep: span2a,4a,2b,4b, then span8..span128. Top: 8-step scan.
// Down-sweep: 5 descend levels + bottom (exact fp32 mat-vecs over m).
// ============================================================================

#define D 256
#define DD 65536

typedef __attribute__((ext_vector_type(8))) short short8;
typedef __attribute__((ext_vector_type(4))) float f4;

__device__ __forceinline__ float bf2f(unsigned short u) {
  return __uint_as_float(((unsigned)u) << 16);
}
__device__ __forceinline__ unsigned short f2bf(float f) {
  unsigned u = __float_as_uint(f);
  u += 0x7FFFu + ((u >> 16) & 1u);          // round-to-nearest-even
  return (unsigned short)(u >> 16);
}
// fragment-order slot lane index (see R3): frag reads lane-contiguous b128.
#define LSWZ(i15, lq) (((((i15) & 15)) + ((lq) << 4)) ^ (lq))

// out[mat] = devA + devB + devA@devB (bf16 dev out), MFMA 16x16x32 bf16.
// 64x64 tile/block (16 blocks/mat), 4 waves, full K=256 staged once.
// Block swizzle: xcd = bx&7; all 16 tiles of a mat on the same XCD,
// mats consecutive per XCD (requires gridDim/16 divisible by 8).
__global__ __launch_bounds__(256) void gemm_mfma(
    const float* __restrict__ aF, const unsigned short* __restrict__ aBf,
    long aMul, long aOff,
    const float* __restrict__ bF, const unsigned short* __restrict__ bBf,
    long bMul, long bOff,
    unsigned short* __restrict__ out)
{
  __shared__ __attribute__((aligned(16))) unsigned short As[32768]; // A:0..16K, B:16K..32K
  unsigned short* Bs = As + 16384;

  const int  bx  = blockIdx.x;
  const int  nmb = ((int)gridDim.x) >> 4;         // mats this dispatch (mult of 8)
  const int  xcd = bx & 7, q = bx >> 3;
  const long mat = (long)(xcd * (nmb >> 3)) + (q >> 4);
  const int  tile = q & 15;
  const int  m0 = (tile >> 2) << 6, n0 = (tile & 3) << 6;
  const long aBase = (mat * aMul + aOff) * (long)DD;
  const long bBase = (mat * bMul + bOff) * (long)DD;
  const int t = threadIdx.x;
  const int w = t >> 6, l = t & 63, lm = l & 15, lq4 = l >> 4;
  const int lswz = l ^ lq4;

  // ---- stage A rows [m0,m0+64) x k[0,256)
  if (aF) {
#pragma unroll
    for (int p = 0; p < 16; ++p) {
      const int idx = (p << 10) + (t << 2);       // float index
      const int r = idx >> 8, k = idx & 255;      // k multiple of 4
      const int gi = m0 + r;
      float4 v = *(const float4*)(aF + aBase + (long)gi * D + k);
      v.x -= (gi == k + 0) ? 1.f : 0.f;
      v.y -= (gi == k + 1) ? 1.f : 0.f;
      v.z -= (gi == k + 2) ? 1.f : 0.f;
      v.w -= (gi == k + 3) ? 1.f : 0.f;
      const int lq = (k >> 3) & 3;
      const int slot = (((r >> 4) << 3) + (k >> 5)) * 64 + LSWZ(r, lq);
      ushort4 o = { f2bf(v.x), f2bf(v.y), f2bf(v.z), f2bf(v.w) };
      *(ushort4*)&As[(slot << 3) + (k & 7)] = o;
    }
  } else {
#pragma unroll
    for (int p = 0; p < 8; ++p) {
      const int sidx = (p << 11) + (t << 3);      // short index, k mult of 8
      const int r = sidx >> 8, k = sidx & 255;
      const uint4 v = *(const uint4*)(aBf + aBase + (long)(m0 + r) * D + k);
      const int lq = (k >> 3) & 3;
      const int slot = (((r >> 4) << 3) + (k >> 5)) * 64 + LSWZ(r, lq);
      *(uint4*)&As[slot << 3] = v;
    }
  }
  // ---- stage B cols [n0,n0+64) x k[0,256) (register transpose)
  {
    const int n4 = (t & 15) << 2;
    const int kb0 = (t >> 4) << 3;
#pragma unroll
    for (int kp = 0; kp < 2; ++kp) {
      const int k8 = kb0 + (kp << 7);
      __attribute__((aligned(16))) unsigned short tmp[4][8];
      if (bF) {
#pragma unroll
        for (int kk = 0; kk < 8; ++kk) {
          const int gk = k8 + kk, gn = n0 + n4;
          float4 v = *(const float4*)(bF + bBase + (long)gk * D + gn);
          v.x -= (gk == gn + 0) ? 1.f : 0.f;
          v.y -= (gk == gn + 1) ? 1.f : 0.f;
          v.z -= (gk == gn + 2) ? 1.f : 0.f;
          v.w -= (gk == gn + 3) ? 1.f : 0.f;
          tmp[0][kk] = f2bf(v.x); tmp[1][kk] = f2bf(v.y);
          tmp[2][kk] = f2bf(v.z); tmp[3][kk] = f2bf(v.w);
        }
      } else {
#pragma unroll
        for (int kk = 0; kk < 8; ++kk) {
          const ushort4 v = *(const ushort4*)(bBf + bBase + (long)(k8 + kk) * D + n0 + n4);
          tmp[0][kk] = v.x; tmp[1][kk] = v.y; tmp[2][kk] = v.z; tmp[3][kk] = v.w;
        }
      }
      const int lq = (k8 >> 3) & 3, kt = k8 >> 5;
#pragma unroll
      for (int jj = 0; jj < 4; ++jj) {
        const int n = n4 + jj;
        const int slot = (((n >> 4) << 3) + kt) * 64 + LSWZ(n, lq);
        *(uint4*)&Bs[slot << 3] = *(const uint4*)&tmp[jj][0];
      }
    }
  }
  __syncthreads();

  // ---- MFMA: lane-contiguous frag reads, 32 MFMA/wave over K=256
  f4 acc[4] = {{0.f,0.f,0.f,0.f},{0.f,0.f,0.f,0.f},
               {0.f,0.f,0.f,0.f},{0.f,0.f,0.f,0.f}};
#pragma unroll
  for (int kt = 0; kt < 8; ++kt) {
    const short8 a = *(const short8*)&As[((((w << 3) + kt) << 6) + lswz) << 3];
#pragma unroll
    for (int f = 0; f < 4; ++f) {
      const short8 b = *(const short8*)&Bs[((((f << 3) + kt) << 6) + lswz) << 3];
      acc[f] = __builtin_amdgcn_mfma_f32_16x16x32_bf16(a, b, acc[f], 0, 0, 0);
    }
  }

  // ---- epilogue: s = acc + devA + devB, both read from resident LDS tiles
  float sv[4][4];
#pragma unroll
  for (int f = 0; f < 4; ++f) {
    const int gj_l = (f << 4) + lm;               // local col
    const int gj   = n0 + gj_l;                   // A's k index
    const int lqA  = (gj >> 3) & 3;
#pragma unroll
    for (int r = 0; r < 4; ++r) {
      const int gi_l = (w << 4) + (lq4 << 2) + r; // local row
      const int giG  = m0 + gi_l;                 // B's k index
      const int slotA = (((gi_l >> 4) << 3) + (gj >> 5)) * 64 + LSWZ(gi_l, lqA);
      const float da = bf2f(As[(slotA << 3) + (gj & 7)]);
      const int lqB  = (giG >> 3) & 3;
      const int slotB = (((gj_l >> 4) << 3) + (giG >> 5)) * 64 + LSWZ(gj_l, lqB);
      const float db = bf2f(Bs[(slotB << 3) + (giG & 7)]);
      sv[f][r] = acc[f][r] + da + db;
    }
  }
  __syncthreads();                                // all LDS reads done

  // ---- C restage (pitch 66: conflict-free b16 writes) then coalesced store
  unsigned short* Cs = As;                        // reuse (4224 shorts)
#pragma unroll
  for (int f = 0; f < 4; ++f)
#pragma unroll
    for (int r = 0; r < 4; ++r)
      Cs[((w << 4) + (lq4 << 2) + r) * 66 + (f << 4) + lm] = f2bf(sv[f][r]);
  __syncthreads();
  {
    const int row = t >> 2, c0 = (t & 3) << 4;    // 16 shorts per thread
    const unsigned int* Cw = (const unsigned int*)Cs;
    const int wb = row * 33 + ((t & 3) << 3);
    unsigned int wbuf[8];
#pragma unroll
    for (int i = 0; i < 8; ++i) wbuf[i] = Cw[wb + i];
    unsigned short* og = out + mat * (long)DD + (long)(m0 + row) * D + n0 + c0;
    uint4 o0 = { wbuf[0], wbuf[1], wbuf[2], wbuf[3] };
    uint4 o1 = { wbuf[4], wbuf[5], wbuf[6], wbuf[7] };
    *(uint4*)og = o0;
    *((uint4*)og + 1) = o1;
  }
}

// 1 WG x 1024 threads: w8[g] = prefix vector at mat 128g, over span-128 devs
__global__ __launch_bounds__(1024) void scan_top8(
    const float* __restrict__ x, const unsigned short* __restrict__ S,
    float* __restrict__ w8)
{
  __shared__ float v[D];
  __shared__ float ps[4][D];
  const int t = threadIdx.x, col = t & 255, kq = t >> 8;
  if (t < D) v[t] = x[t];
  __syncthreads();
  for (int g = 0; g < 8; ++g) {
    if (t < D) w8[g * D + t] = v[t];
    const unsigned short* M = S + (long)g * DD + (long)(kq * 64) * D + col;
    float acc = 0.f;
#pragma unroll 8
    for (int i = 0; i < 64; ++i)
      acc += v[kq * 64 + i] * bf2f(M[(long)i * D]);
    ps[kq][col] = acc;
    __syncthreads();
    if (t < D) v[t] += ps[0][t] + ps[1][t] + ps[2][t] + ps[3][t];
    __syncthreads();
  }
}

// WG g (1024 thr): dst[2g] = src[g]; dst[2g+1] = src[g] @ (I + dev mats[2g])
__global__ __launch_bounds__(1024) void descend(
    const float* __restrict__ src, const unsigned short* __restrict__ mats,
    float* __restrict__ dst)
{
  __shared__ float v[D];
  __shared__ float ps[4][D];
  const int g = blockIdx.x, t = threadIdx.x, col = t & 255, kq = t >> 8;
  if (t < D) v[t] = src[(long)g * D + t];
  __syncthreads();
  if (t < D) dst[(long)(2 * g) * D + t] = v[t];
  const unsigned short* M = mats + (long)(2 * g) * DD + (long)(kq * 64) * D + col;
  float acc = 0.f;
#pragma unroll 8
  for (int i = 0; i < 64; ++i)
    acc += v[kq * 64 + i] * bf2f(M[(long)i * D]);
  ps[kq][col] = acc;
  __syncthreads();
  if (t < D)
    dst[(long)(2 * g + 1) * D + t] = v[t] + ps[0][t] + ps[1][t] + ps[2][t] + ps[3][t];
}

// WG c (1024 thr): res[4c] = u[c]; then 3 (4 for c=255) exact fp32 mat-vecs
__global__ __launch_bounds__(1024) void bottom(
    const float* __restrict__ u, const float* __restrict__ m,
    float* __restrict__ out)
{
  __shared__ float v[D];
  __shared__ float ps[4][D];
  const int c = blockIdx.x, t = threadIdx.x, col = t & 255, kq = t >> 8;
  if (t < D) v[t] = u[(long)c * D + t];
  __syncthreads();
  if (t < D) out[(long)(4 * c) * D + t] = v[t];
  const int steps = (c == 255) ? 4 : 3;
  for (int s = 0; s < steps; ++s) {
    const float* M = m + (long)(4 * c + s) * DD + (long)(kq * 64) * D + col;
    float acc = 0.f;
#pragma unroll 8
    for (int i = 0; i < 64; ++i)
      acc += v[kq * 64 + i] * M[(long)i * D];
    ps[kq][col] = acc;
    __syncthreads();
    if (t < D) {
      float s2 = ps[0][t] + ps[1][t] + ps[2][t] + ps[3][t];
      v[t] = s2;
      out[(long)(4 * c + s + 1) * D + t] = s2;
    }
    __syncthreads();
  }
}

// correctness-only fallback if ws is too small: fully sequential chain
__global__ __launch_bounds__(256) void fallback_seq(
    const float* __restrict__ x, const float* __restrict__ m,
    float* __restrict__ out)
{
  __shared__ float v[D];
  const int t = threadIdx.x;
  v[t] = x[t];
  __syncthreads();
  for (int k = 0; k < 1024; ++k) {
    out[(long)k * D + t] = v[t];
    const float* M = m + (long)k * DD;
    float acc = 0.f;
    for (int i = 0; i < D; ++i) acc += v[i] * M[(long)i * D + t];
    __syncthreads();
    v[t] = acc;
    __syncthreads();
  }
  out[(long)1024 * D + t] = v[t];
}

extern "C" void kernel_launch(void* const* d_in, const int* in_sizes, int n_in,
                              void* d_out, int out_size, void* d_ws, size_t ws_size,
                              hipStream_t stream) {
  const float* x = (const float*)d_in[0];   // [1,256] fp32
  const float* m = (const float*)d_in[1];   // [1024,256,256] fp32
  float* out = (float*)d_out;               // [1025,256] fp32

  const size_t NEED = 67624960;             // 64 MiB mats + 504 KiB vectors
  if (ws_size < NEED) {
    fallback_seq<<<1, 256, 0, stream>>>(x, m, out);
    return;
  }

  char* w8 = (char*)d_ws;
  // buf0 [0,32M): T2a -> T2b (transient span-2), later Q2/Q4/Rm/S64/S128
  unsigned short* buf0 = (unsigned short*)(w8);
  unsigned short* Qb   = (unsigned short*)(w8 + 33554432);   // [32M,64M) span-4, 256 mats
  unsigned short* Q2   = (unsigned short*)(w8);              // 16 MiB span-8   (128)
  unsigned short* Q4   = (unsigned short*)(w8 + 16777216);   // 8 MiB  span-16  (64)
  unsigned short* Rm   = (unsigned short*)(w8 + 25165824);   // 4 MiB  span-32  (32)
  unsigned short* S64  = (unsigned short*)(w8 + 29360128);   // 2 MiB  span-64  (16)
  unsigned short* S128 = (unsigned short*)(w8 + 31457280);   // 1 MiB  span-128 (8)
  float* wv  = (float*)(w8 + 67108864);
  float* w8v = wv;                 // 8 x 256
  float* w16 = wv + 2048;          // 16 x 256
  float* w32 = wv + 6144;          // 32 x 256
  float* u4  = wv + 14336;         // 64 x 256
  float* u2  = wv + 30720;         // 128 x 256
  float* uu  = wv + 63488;         // 256 x 256

  const dim3 blk(256), vblk(1024);
  // up-sweep tree (split halves so span-2 fits in 32 MiB):
  // span2a: T2a[e] = dev(m[2e] @ m[2e+1]), e in [0,256)
  gemm_mfma<<<dim3(4096), blk, 0, stream>>>(m, nullptr, 2, 0, m, nullptr, 2, 1, buf0);
  // span4a: Q[c] = T2a[2c] (*) T2a[2c+1], c in [0,128)
  gemm_mfma<<<dim3(2048), blk, 0, stream>>>(nullptr, buf0, 2, 0, nullptr, buf0, 2, 1, Qb);
  // span2b: T2b[e] = dev(m[512+2e] @ m[512+2e+1])
  gemm_mfma<<<dim3(4096), blk, 0, stream>>>(m + 512L * DD, nullptr, 2, 0,
                                            m + 512L * DD, nullptr, 2, 1, buf0);
  // span4b: Q[128+c]
  gemm_mfma<<<dim3(2048), blk, 0, stream>>>(nullptr, buf0, 2, 0, nullptr, buf0, 2, 1,
                                            Qb + 128L * DD);
  // higher tree levels
  gemm_mfma<<<dim3(2048), blk, 0, stream>>>(nullptr, Qb, 2, 0, nullptr, Qb, 2, 1, Q2);
  gemm_mfma<<<dim3(1024), blk, 0, stream>>>(nullptr, Q2, 2, 0, nullptr, Q2, 2, 1, Q4);
  gemm_mfma<<<dim3(512),  blk, 0, stream>>>(nullptr, Q4, 2, 0, nullptr, Q4, 2, 1, Rm);
  gemm_mfma<<<dim3(256),  blk, 0, stream>>>(nullptr, Rm, 2, 0, nullptr, Rm, 2, 1, S64);
  gemm_mfma<<<dim3(128),  blk, 0, stream>>>(nullptr, S64, 2, 0, nullptr, S64, 2, 1, S128);
  // top sequential scan over the 8 span-128 products
  scan_top8<<<dim3(1), vblk, 0, stream>>>(x, S128, w8v);
  // vector down-sweep
  descend<<<dim3(8),   vblk, 0, stream>>>(w8v, S64, w16);
  descend<<<dim3(16),  vblk, 0, stream>>>(w16, Rm,  w32);
  descend<<<dim3(32),  vblk, 0, stream>>>(w32, Q4,  u4);
  descend<<<dim3(64),  vblk, 0, stream>>>(u4,  Q2,  u2);
  descend<<<dim3(128), vblk, 0, stream>>>(u2,  Qb,  uu);
  // bottom: exact fp32 matvecs over m, emit all output rows
  bottom<<<dim3(256), vblk, 0, stream>>>(uu, m, out);
}